// Round 1
// baseline (150.712 us; speedup 1.0000x reference)
//
#include <hip/hip_runtime.h>

#define DIMS 128
#define NCLS 16
#define NPROJ 32  // src 16 + dst 16

// ---------------- Phase 1: per-node projection P[n][32] ----------------
// P[n][c]      = sum_d h[n][d] * W[c][d]        (c in 0..15, src half)
// P[n][16+c]   = sum_d h[n][d] * W[c][128+d]    (dst half)
__global__ __launch_bounds__(256) void proj_kernel(
    const float* __restrict__ h, const float* __restrict__ W,
    float* __restrict__ P, int n_nodes) {
  // Re-layout W into lw[32][128]: rows 0..15 = W_src, rows 16..31 = W_dst
  __shared__ float lw[NPROJ * DIMS];  // 16 KB
  for (int idx = threadIdx.x; idx < NPROJ * DIMS; idx += 256) {
    int c = idx >> 7;         // 0..31
    int d = idx & 127;
    lw[idx] = W[(c & 15) * 256 + ((c >> 4) << 7) + d];
  }
  __syncthreads();

  int node = blockIdx.x * blockDim.x + threadIdx.x;
  if (node >= n_nodes) return;

  const float4* h4 = reinterpret_cast<const float4*>(h + (size_t)node * DIMS);
  const float4* lw4 = reinterpret_cast<const float4*>(lw);

  float acc[NPROJ];
#pragma unroll
  for (int c = 0; c < NPROJ; ++c) acc[c] = 0.f;

#pragma unroll 4
  for (int dc = 0; dc < DIMS / 4; ++dc) {   // 32 float4 chunks of h row
    float4 hv = h4[dc];
#pragma unroll
    for (int c = 0; c < NPROJ; ++c) {
      float4 wv = lw4[c * (DIMS / 4) + dc];  // wave-uniform LDS read -> broadcast
      float a = acc[c];
      a = fmaf(hv.x, wv.x, a);
      a = fmaf(hv.y, wv.y, a);
      a = fmaf(hv.z, wv.z, a);
      a = fmaf(hv.w, wv.w, a);
      acc[c] = a;
    }
  }

  float4* Po = reinterpret_cast<float4*>(P + (size_t)node * NPROJ);
#pragma unroll
  for (int q = 0; q < NPROJ / 4; ++q) {
    Po[q] = make_float4(acc[q * 4 + 0], acc[q * 4 + 1],
                        acc[q * 4 + 2], acc[q * 4 + 3]);
  }
}

// ---------------- Phase 2: per-edge gather + add ----------------
// thread t -> edge e = t/16, class c = t%16
// out[e][c] = P[src[e]][c] + P[dst[e]][16+c] + b[c]
__global__ __launch_bounds__(256) void gather_kernel(
    const int* __restrict__ esrc, const int* __restrict__ edst,
    const float* __restrict__ P, const float* __restrict__ b,
    float* __restrict__ out, int n_edges) {
  long t = (long)blockIdx.x * blockDim.x + threadIdx.x;
  int e = (int)(t >> 4);
  if (e >= n_edges) return;
  int c = (int)(t & 15);
  int s = esrc[e];
  int d = edst[e];
  out[t] = P[(size_t)s * NPROJ + c] + P[(size_t)d * NPROJ + NCLS + c] + b[c];
}

// ---------------- Fallback (only if workspace too small) ----------------
__global__ __launch_bounds__(256) void direct_kernel(
    const float* __restrict__ h, const int* __restrict__ esrc,
    const int* __restrict__ edst, const float* __restrict__ W,
    const float* __restrict__ b, float* __restrict__ out, int n_edges) {
  __shared__ float lw[NCLS * 2 * DIMS];
  for (int idx = threadIdx.x; idx < NCLS * 2 * DIMS; idx += 256) lw[idx] = W[idx];
  __syncthreads();
  long t = (long)blockIdx.x * blockDim.x + threadIdx.x;
  int e = (int)(t >> 4);
  if (e >= n_edges) return;
  int c = (int)(t & 15);
  const float* hs = h + (size_t)esrc[e] * DIMS;
  const float* hd = h + (size_t)edst[e] * DIMS;
  float acc = b[c];
  for (int d0 = 0; d0 < DIMS; ++d0) {
    acc = fmaf(hs[d0], lw[c * 256 + d0], acc);
    acc = fmaf(hd[d0], lw[c * 256 + DIMS + d0], acc);
  }
  out[t] = acc;
}

extern "C" void kernel_launch(void* const* d_in, const int* in_sizes, int n_in,
                              void* d_out, int out_size, void* d_ws, size_t ws_size,
                              hipStream_t stream) {
  const float* h    = (const float*)d_in[0];
  const int*   esrc = (const int*)d_in[1];
  const int*   edst = (const int*)d_in[2];
  const float* W    = (const float*)d_in[3];
  const float* b    = (const float*)d_in[4];
  float* out = (float*)d_out;

  int n_nodes = in_sizes[0] / DIMS;
  int n_edges = in_sizes[1];

  size_t need = (size_t)n_nodes * NPROJ * sizeof(float);
  if (ws_size >= need) {
    float* P = (float*)d_ws;
    int blocks1 = (n_nodes + 255) / 256;
    proj_kernel<<<blocks1, 256, 0, stream>>>(h, W, P, n_nodes);
    long total = (long)n_edges * NCLS;
    int blocks2 = (int)((total + 255) / 256);
    gather_kernel<<<blocks2, 256, 0, stream>>>(esrc, edst, P, b, out, n_edges);
  } else {
    long total = (long)n_edges * NCLS;
    int blocks2 = (int)((total + 255) / 256);
    direct_kernel<<<blocks2, 256, 0, stream>>>(h, esrc, edst, W, b, out, n_edges);
  }
}